// Round 8
// baseline (201.347 us; speedup 1.0000x reference)
//
#include <hip/hip_runtime.h>
#include <math.h>

// MMD loss, total = concat(source, target) [8192 x 256] f32.
// L2[i][j] = max(||ti||^2 + ||tj||^2 - 2 ti.tj, 0)
// bandwidth = sum(L2)/(n^2-n)/4, analytic: sum(L2) = 2n*S1 - 2*||sum_i ti||^2
// kernels = sum_{i=0..4} exp(-L2/(bw*2^i + 1e-9))
// outputs: [loss, max(L2), xx, yy, xy, yx]  (6 f32)
//
// Round 8 vs round 6/7:
//  - r7 lesson: dbuf at 66KB LDS (2 blk/CU) LOST to single-buf at 33KB (4 blk/CU).
//    This round: BK=32 double-buffer = 32KB LDS -> dbuf AND 4 blk/CU.
//  - new chunk-major global bf16 layout: 8 chunks of 64B/row; row-pairs share a
//    128B line; 16B granule g=(row&1)*4+b16 stored at pos g^(rp&7). Stage is
//    linear per panel (global_load_lds), ds_read_b128 conflict-free per 8-lane
//    service group (all 8 slots hit once).
//  - keep r7's fusions: bw-reduction in prep (last-block ticket), final in gram.

constexpr int NTOT  = 8192;
constexpr int BHALF = 4096;
constexpr int DIM   = 256;
constexpr int BM    = 128;
constexpr size_t CHUNK_BYTES = (size_t)(NTOT / 2) * 128;   // 524288 B per K-chunk

typedef __attribute__((ext_vector_type(8))) short bf16x8;
typedef __attribute__((ext_vector_type(4))) float f32x4;

#define GLOAD_LDS16(gp, lp)                                                      \
    __builtin_amdgcn_global_load_lds(                                            \
        (__attribute__((address_space(1))) const void*)(gp),                     \
        (__attribute__((address_space(3))) void*)(lp), 16, 0, 0)

// ws layout (bytes):
//   0       : double qsum[4]
//   32      : int    maxBits
//   36      : float  bandwidth
//   40      : int    gramCounter
//   44      : int    prepCounter
//   2112    : float  sq[8192]          (32 KB)
//   36864   : ushort hi[8192*256]      (4 MB, chunk-major swizzled, see above)
//   4231168 : float  colpart[256][256] (256 KB per-block partial column sums)
//   4493312 : float  sqpart[256]       (1 KB per-block partial sums of sq)

__device__ __forceinline__ unsigned short rne_bf16(float f) {
    unsigned u = __float_as_uint(f);
    return (unsigned short)((u + 0x7fffu + ((u >> 16) & 1u)) >> 16);
}

// Fused: row norms (sq), column partial sums, f32 -> bf16 chunk-major swizzled,
// and (last block) the bandwidth reduction.
__global__ __launch_bounds__(256) void prep_kernel(
        const float* __restrict__ src, const float* __restrict__ tgt,
        float* __restrict__ sq, float* __restrict__ colpart,
        float* __restrict__ sqpart, unsigned short* __restrict__ hi,
        int* __restrict__ prepCounter, float* __restrict__ bwp) {
    __shared__ float  cs[4][256];
    __shared__ float  sblk[256];
    __shared__ double red[256];
    __shared__ unsigned lastFlag;
    const int t = threadIdx.x;
    const int w = t >> 6, l = t & 63;
    const int c   = l >> 3;            // K-chunk 0..7 (32 elems each)
    const int b16 = (l & 7) >> 1;      // granule index within chunk
    const int hs  = (l & 1) * 8;       // half of granule
    float c0 = 0.f, c1 = 0.f, c2 = 0.f, c3 = 0.f;
    float sqacc = 0.f;

#pragma unroll
    for (int it = 0; it < 8; ++it) {
        const int row = blockIdx.x * 32 + w * 8 + it;
        const float* p = (row < BHALF) ? src + (size_t)row * DIM
                                       : tgt + (size_t)(row - BHALF) * DIM;
        float4 v = reinterpret_cast<const float4*>(p)[l];
        float s = v.x * v.x + v.y * v.y + v.z * v.z + v.w * v.w;
        sqacc += s;
#pragma unroll
        for (int off = 32; off; off >>= 1) s += __shfl_down(s, off);
        if (l == 0) sq[row] = s;
        c0 += v.x; c1 += v.y; c2 += v.z; c3 += v.w;

        unsigned hp0 = (unsigned)rne_bf16(v.x) | ((unsigned)rne_bf16(v.y) << 16);
        unsigned hp1 = (unsigned)rne_bf16(v.z) | ((unsigned)rne_bf16(v.w) << 16);
        const int rp = row >> 1;
        const int g  = ((row & 1) << 2) | b16;
        const size_t byteoff = (size_t)c * CHUNK_BYTES + (size_t)rp * 128
                             + 16 * (g ^ (rp & 7)) + hs;
        *reinterpret_cast<uint2*>((char*)hi + byteoff) = make_uint2(hp0, hp1);
    }

    cs[w][l * 4 + 0] = c0; cs[w][l * 4 + 1] = c1;
    cs[w][l * 4 + 2] = c2; cs[w][l * 4 + 3] = c3;
    sblk[t] = sqacc;
    __syncthreads();
    colpart[blockIdx.x * 256 + t] = cs[0][t] + cs[1][t] + cs[2][t] + cs[3][t];
    for (int off = 128; off; off >>= 1) {
        if (t < off) sblk[t] += sblk[t + off];
        __syncthreads();
    }
    if (t == 0) sqpart[blockIdx.x] = sblk[0];

    // ---- last block reduces bandwidth ----
    __threadfence();
    if (t == 0) lastFlag = (atomicAdd(prepCounter, 1) == (NTOT / 32 - 1)) ? 1u : 0u;
    __syncthreads();
    if (lastFlag) {
        __threadfence();
        double v = 0.0;
        for (int b = 0; b < 256; ++b) v += (double)colpart[b * 256 + t];
        red[t] = v * v; __syncthreads();
        for (int off = 128; off; off >>= 1) {
            if (t < off) red[t] += red[t + off];
            __syncthreads();
        }
        double V2 = red[0]; __syncthreads();
        red[t] = (double)sqpart[t]; __syncthreads();
        for (int off = 128; off; off >>= 1) {
            if (t < off) red[t] += red[t + off];
            __syncthreads();
        }
        if (t == 0) {
            double S1 = red[0];
            const double n = (double)NTOT;
            double sumL2 = 2.0 * n * S1 - 2.0 * V2;
            *bwp = (float)(sumL2 / (n * n - n) / 4.0);
        }
    }
}

__global__ __launch_bounds__(256) void gram_kernel(
        const unsigned short* __restrict__ hi,
        const float* __restrict__ sq, const float* __restrict__ bwp,
        double* __restrict__ qsum, int* __restrict__ maxBits,
        int* __restrict__ gramCounter, float* __restrict__ out) {
    // XCD-aware swizzle over the 2080-block upper triangle (2080 = 8*260)
    const int tb = blockIdx.x;
    const int id = (tb & 7) * 260 + (tb >> 3);
    int k = 2079 - id;
    int u = (int)((sqrt((double)(8 * k + 1)) - 1.0) * 0.5);
    while ((u + 1) * (u + 2) / 2 <= k) ++u;
    while (u * (u + 1) / 2 > k) --u;
    const int by = 63 - u;
    const int bx = 63 - (k - u * (u + 1) / 2);
    const bool diag = (bx == by);

    __shared__ alignas(16) char ldsA[2][8192];   // 2 x 8 KB (128 rows x 64 B)
    __shared__ alignas(16) char ldsB[2][8192];
    __shared__ double sred[4];
    __shared__ float  mred[4];
    __shared__ unsigned lastFlag;

    const int i0 = by * BM;
    const int j0 = bx * BM;
    const char* Abase = (const char*)hi + (size_t)(i0 >> 1) * 128;
    const char* Bbase = (const char*)hi + (size_t)(j0 >> 1) * 128;

    const int t    = threadIdx.x;
    const int lane = t & 63;
    const int w    = t >> 6;       // 4 waves, 2x2 over the 128x128 tile
    const int wr   = w >> 1;
    const int wc   = w & 1;
    const int l15  = lane & 15;
    const int q    = lane >> 4;

    // per-thread fragment offset: row rL = half*64 + mt*16 + l15
    //   rp = rL>>1, pos = (((rL&1)<<2)|q) ^ (rp&7)  ->  folds to constant tail
    const int fragTail = (l15 >> 1) * 128
                       + 16 * (((((l15 & 1) << 2) | q)) ^ (l15 >> 1));
    const int abase = wr * 4096 + fragTail;
    const int bbase = wc * 4096 + fragTail;

    f32x4 acc[4][4] = {};

    auto STAGE = [&](int c, int buf) {
        const size_t cb = (size_t)c * CHUNK_BYTES + lane * 16;
#pragma unroll
        for (int it = 0; it < 2; ++it) {
            const int off = (it * 4 + w) * 1024;       // wave-uniform LDS dest
            GLOAD_LDS16(Abase + cb + off, &ldsA[buf][off]);
            if (!diag) GLOAD_LDS16(Bbase + cb + off, &ldsB[buf][off]);
        }
    };

    STAGE(0, 0);
    __syncthreads();

#pragma unroll
    for (int c = 0; c < 8; ++c) {                  // 8 K-chunks of 32 bf16
        if (c < 7) STAGE(c + 1, (c + 1) & 1);      // prefetch into other buffer
        const char* ab = ldsA[c & 1];
        const char* bb = diag ? ldsA[c & 1] : ldsB[c & 1];
        bf16x8 a[4], b[4];
#pragma unroll
        for (int mt = 0; mt < 4; ++mt)
            a[mt] = *reinterpret_cast<const bf16x8*>(ab + abase + mt * 1024);
#pragma unroll
        for (int nt = 0; nt < 4; ++nt)
            b[nt] = *reinterpret_cast<const bf16x8*>(bb + bbase + nt * 1024);
#pragma unroll
        for (int mt = 0; mt < 4; ++mt)
#pragma unroll
            for (int nt = 0; nt < 4; ++nt)
                acc[mt][nt] = __builtin_amdgcn_mfma_f32_16x16x32_bf16(
                    a[mt], b[nt], acc[mt][nt], 0, 0, 0);
        __syncthreads();   // drains prefetch (issued before ds_read+MFMA above)
    }

    // ---- epilogue: L2, max, 5-kernel exp sum via squaring chain ----
    const float bw  = *bwp;
    const float ic4 = -1.44269504088896340736f / (bw * 16.0f + 1e-9f);

    float m = 0.0f;
    float ksum = 0.0f;
    const int rbase = i0 + wr * 64 + q * 4;
    const int cbase = j0 + wc * 64 + l15;
    float sb[4];
#pragma unroll
    for (int nt = 0; nt < 4; ++nt) sb[nt] = sq[cbase + nt * 16];
#pragma unroll
    for (int mt = 0; mt < 4; ++mt) {
        float sa[4];
#pragma unroll
        for (int r = 0; r < 4; ++r) sa[r] = sq[rbase + mt * 16 + r];
#pragma unroll
        for (int nt = 0; nt < 4; ++nt)
#pragma unroll
            for (int r = 0; r < 4; ++r) {
                float l2 = fmaxf(fmaf(-2.0f, acc[mt][nt][r], sa[r] + sb[nt]), 0.0f);
                m = fmaxf(m, l2);
                float e1  = exp2f(l2 * ic4);
                float e2  = e1 * e1;
                float e4  = e2 * e2;
                float e8  = e4 * e4;
                float e16 = e8 * e8;
                ksum += (e1 + e2) + (e4 + e8) + e16;
            }
    }

    double s = (double)ksum;
#pragma unroll
    for (int off = 32; off; off >>= 1) {
        s += __shfl_down(s, off);
        m  = fmaxf(m, __shfl_down(m, off));
    }
    if ((t & 63) == 0) { sred[w] = s; mred[w] = m; }
    __syncthreads();
    if (t == 0) {
        double st = sred[0] + sred[1] + sred[2] + sred[3];
        float  mt = fmaxf(fmaxf(mred[0], mred[1]), fmaxf(mred[2], mred[3]));
        atomicMax(maxBits, __float_as_int(mt));
        const int qq = (((i0 >= BHALF) ? 2 : 0) | ((j0 >= BHALF) ? 1 : 0));
        const int qT = (((j0 >= BHALF) ? 2 : 0) | ((i0 >= BHALF) ? 1 : 0));
        if (diag) {
            atomicAdd(&qsum[qq], st);
        } else if (qq == qT) {
            atomicAdd(&qsum[qq], 2.0 * st);      // mirror lower triangle
        } else {
            atomicAdd(&qsum[qq], st);
            atomicAdd(&qsum[qT], st);
        }
        __threadfence();
        lastFlag = (atomicAdd(gramCounter, 1) == 2079) ? 1u : 0u;
    }
    __syncthreads();
    if (lastFlag && t == 0) {
        __threadfence();
        double xx = atomicAdd(&qsum[0], 0.0);    // atomic-RMW: cross-XCD coherent
        double xy = atomicAdd(&qsum[1], 0.0);
        double yx = atomicAdd(&qsum[2], 0.0);
        double yy = atomicAdd(&qsum[3], 0.0);
        int    mb = atomicMax(maxBits, 0);
        const double denom = (double)BHALF * (double)BHALF;
        xx /= denom; xy /= denom; yx /= denom; yy /= denom;
        out[0] = (float)(xx + yy - xy - yx);
        out[1] = __int_as_float(mb);
        out[2] = (float)xx;
        out[3] = (float)yy;
        out[4] = (float)xy;
        out[5] = (float)yx;
    }
}

extern "C" void kernel_launch(void* const* d_in, const int* in_sizes, int n_in,
                              void* d_out, int out_size, void* d_ws, size_t ws_size,
                              hipStream_t stream) {
    const float* src = (const float*)d_in[0];
    const float* tgt = (const float*)d_in[1];
    float* out = (float*)d_out;

    double* qsum     = (double*)d_ws;
    int*    maxB     = (int*)   ((char*)d_ws + 32);
    float*  bwp      = (float*) ((char*)d_ws + 36);
    int*    gramCnt  = (int*)   ((char*)d_ws + 40);
    int*    prepCnt  = (int*)   ((char*)d_ws + 44);
    float*  sq       = (float*) ((char*)d_ws + 2112);
    unsigned short* hi = (unsigned short*)((char*)d_ws + 36864);
    float*  colpart  = (float*) ((char*)d_ws + 36864 + (size_t)NTOT * DIM * 2);
    float*  sqpart   = (float*) ((char*)d_ws + 36864 + (size_t)NTOT * DIM * 2 + 256 * 256 * 4);

    hipMemsetAsync(d_ws, 0, 64, stream);

    prep_kernel<<<NTOT / 32, 256, 0, stream>>>(src, tgt, sq, colpart, sqpart, hi,
                                               prepCnt, bwp);
    gram_kernel<<<2080, 256, 0, stream>>>(hi, sq, bwp, qsum, maxB, gramCnt, out);
}

// Round 9
// 199.861 us; speedup vs baseline: 1.0074x; 1.0074x over previous
//
#include <hip/hip_runtime.h>
#include <math.h>

// MMD loss, total = concat(source, target) [8192 x 256] f32.
// L2[i][j] = max(||ti||^2 + ||tj||^2 - 2 ti.tj, 0)
// bandwidth = sum(L2)/(n^2-n)/4, analytic: sum(L2) = 2n*S1 - 2*||sum_i ti||^2
// kernels = sum_{i=0..4} exp(-L2/(bw*2^i + 1e-9))
// outputs: [loss, max(L2), xx, yy, xy, yx]  (6 f32)
//
// Round 9 vs round 8 (single change, mechanism-targeted):
//  r7/r8 issued STAGE(c+1) BEFORE the ds_reads of buf[c]; the compiler can't
//  disprove aliasing between gload_lds dest buf[c^1] and ds_read src buf[c],
//  so it drains vmcnt(0) BEFORE the ds_reads -> prefetch never overlapped.
//  Now: ds_read(buf c) -> STAGE(c+1) -> MFMA -> barrier. The stage flies
//  during the MFMA cluster; the only drain is the pre-barrier vmcnt(0).

constexpr int NTOT  = 8192;
constexpr int BHALF = 4096;
constexpr int DIM   = 256;
constexpr int BM    = 128;
constexpr size_t CHUNK_BYTES = (size_t)(NTOT / 2) * 128;   // 524288 B per K-chunk

typedef __attribute__((ext_vector_type(8))) short bf16x8;
typedef __attribute__((ext_vector_type(4))) float f32x4;

#define GLOAD_LDS16(gp, lp)                                                      \
    __builtin_amdgcn_global_load_lds(                                            \
        (__attribute__((address_space(1))) const void*)(gp),                     \
        (__attribute__((address_space(3))) void*)(lp), 16, 0, 0)

// ws layout (bytes):
//   0       : double qsum[4]
//   32      : int    maxBits
//   36      : float  bandwidth
//   40      : int    gramCounter
//   44      : int    prepCounter
//   2112    : float  sq[8192]          (32 KB)
//   36864   : ushort hi[8192*256]      (4 MB, chunk-major swizzled)
//   4231168 : float  colpart[256][256] (256 KB per-block partial column sums)
//   4493312 : float  sqpart[256]       (1 KB per-block partial sums of sq)

__device__ __forceinline__ unsigned short rne_bf16(float f) {
    unsigned u = __float_as_uint(f);
    return (unsigned short)((u + 0x7fffu + ((u >> 16) & 1u)) >> 16);
}

// Fused: row norms (sq), column partial sums, f32 -> bf16 chunk-major swizzled,
// and (last block) the bandwidth reduction.
__global__ __launch_bounds__(256) void prep_kernel(
        const float* __restrict__ src, const float* __restrict__ tgt,
        float* __restrict__ sq, float* __restrict__ colpart,
        float* __restrict__ sqpart, unsigned short* __restrict__ hi,
        int* __restrict__ prepCounter, float* __restrict__ bwp) {
    __shared__ float  cs[4][256];
    __shared__ float  sblk[256];
    __shared__ double red[256];
    __shared__ unsigned lastFlag;
    const int t = threadIdx.x;
    const int w = t >> 6, l = t & 63;
    const int c   = l >> 3;            // K-chunk 0..7 (32 elems each)
    const int b16 = (l & 7) >> 1;      // granule index within chunk
    const int hs  = (l & 1) * 8;       // half of granule
    float c0 = 0.f, c1 = 0.f, c2 = 0.f, c3 = 0.f;
    float sqacc = 0.f;

#pragma unroll
    for (int it = 0; it < 8; ++it) {
        const int row = blockIdx.x * 32 + w * 8 + it;
        const float* p = (row < BHALF) ? src + (size_t)row * DIM
                                       : tgt + (size_t)(row - BHALF) * DIM;
        float4 v = reinterpret_cast<const float4*>(p)[l];
        float s = v.x * v.x + v.y * v.y + v.z * v.z + v.w * v.w;
        sqacc += s;
#pragma unroll
        for (int off = 32; off; off >>= 1) s += __shfl_down(s, off);
        if (l == 0) sq[row] = s;
        c0 += v.x; c1 += v.y; c2 += v.z; c3 += v.w;

        unsigned hp0 = (unsigned)rne_bf16(v.x) | ((unsigned)rne_bf16(v.y) << 16);
        unsigned hp1 = (unsigned)rne_bf16(v.z) | ((unsigned)rne_bf16(v.w) << 16);
        const int rp = row >> 1;
        const int g  = ((row & 1) << 2) | b16;
        const size_t byteoff = (size_t)c * CHUNK_BYTES + (size_t)rp * 128
                             + 16 * (g ^ (rp & 7)) + hs;
        *reinterpret_cast<uint2*>((char*)hi + byteoff) = make_uint2(hp0, hp1);
    }

    cs[w][l * 4 + 0] = c0; cs[w][l * 4 + 1] = c1;
    cs[w][l * 4 + 2] = c2; cs[w][l * 4 + 3] = c3;
    sblk[t] = sqacc;
    __syncthreads();
    colpart[blockIdx.x * 256 + t] = cs[0][t] + cs[1][t] + cs[2][t] + cs[3][t];
    for (int off = 128; off; off >>= 1) {
        if (t < off) sblk[t] += sblk[t + off];
        __syncthreads();
    }
    if (t == 0) sqpart[blockIdx.x] = sblk[0];

    // ---- last block reduces bandwidth ----
    __threadfence();
    if (t == 0) lastFlag = (atomicAdd(prepCounter, 1) == (NTOT / 32 - 1)) ? 1u : 0u;
    __syncthreads();
    if (lastFlag) {
        __threadfence();
        double v = 0.0;
        for (int b = 0; b < 256; ++b) v += (double)colpart[b * 256 + t];
        red[t] = v * v; __syncthreads();
        for (int off = 128; off; off >>= 1) {
            if (t < off) red[t] += red[t + off];
            __syncthreads();
        }
        double V2 = red[0]; __syncthreads();
        red[t] = (double)sqpart[t]; __syncthreads();
        for (int off = 128; off; off >>= 1) {
            if (t < off) red[t] += red[t + off];
            __syncthreads();
        }
        if (t == 0) {
            double S1 = red[0];
            const double n = (double)NTOT;
            double sumL2 = 2.0 * n * S1 - 2.0 * V2;
            *bwp = (float)(sumL2 / (n * n - n) / 4.0);
        }
    }
}

__global__ __launch_bounds__(256) void gram_kernel(
        const unsigned short* __restrict__ hi,
        const float* __restrict__ sq, const float* __restrict__ bwp,
        double* __restrict__ qsum, int* __restrict__ maxBits,
        int* __restrict__ gramCounter, float* __restrict__ out) {
    // XCD-aware swizzle over the 2080-block upper triangle (2080 = 8*260)
    const int tb = blockIdx.x;
    const int id = (tb & 7) * 260 + (tb >> 3);
    int k = 2079 - id;
    int u = (int)((sqrt((double)(8 * k + 1)) - 1.0) * 0.5);
    while ((u + 1) * (u + 2) / 2 <= k) ++u;
    while (u * (u + 1) / 2 > k) --u;
    const int by = 63 - u;
    const int bx = 63 - (k - u * (u + 1) / 2);
    const bool diag = (bx == by);

    __shared__ alignas(16) char ldsA[2][8192];   // 2 x 8 KB (128 rows x 64 B)
    __shared__ alignas(16) char ldsB[2][8192];
    __shared__ double sred[4];
    __shared__ float  mred[4];
    __shared__ unsigned lastFlag;

    const int i0 = by * BM;
    const int j0 = bx * BM;
    const char* Abase = (const char*)hi + (size_t)(i0 >> 1) * 128;
    const char* Bbase = (const char*)hi + (size_t)(j0 >> 1) * 128;

    const int t    = threadIdx.x;
    const int lane = t & 63;
    const int w    = t >> 6;       // 4 waves, 2x2 over the 128x128 tile
    const int wr   = w >> 1;
    const int wc   = w & 1;
    const int l15  = lane & 15;
    const int q    = lane >> 4;

    // per-thread fragment offset: row rL = half*64 + mt*16 + l15
    //   rp = rL>>1, pos = (((rL&1)<<2)|q) ^ (rp&7)  ->  folds to constant tail
    const int fragTail = (l15 >> 1) * 128
                       + 16 * (((((l15 & 1) << 2) | q)) ^ (l15 >> 1));
    const int abase = wr * 4096 + fragTail;
    const int bbase = wc * 4096 + fragTail;

    f32x4 acc[4][4] = {};

    auto STAGE = [&](int c, int buf) {
        const size_t cb = (size_t)c * CHUNK_BYTES + lane * 16;
#pragma unroll
        for (int it = 0; it < 2; ++it) {
            const int off = (it * 4 + w) * 1024;       // wave-uniform LDS dest
            GLOAD_LDS16(Abase + cb + off, &ldsA[buf][off]);
            if (!diag) GLOAD_LDS16(Bbase + cb + off, &ldsB[buf][off]);
        }
    };

    STAGE(0, 0);
    __syncthreads();

#pragma unroll
    for (int c = 0; c < 8; ++c) {                  // 8 K-chunks of 32 bf16
        const char* ab = ldsA[c & 1];
        const char* bb = diag ? ldsA[c & 1] : ldsB[c & 1];
        // 1) ds_read current buffer FIRST (no alias hazard with this phase's stage)
        bf16x8 a[4], b[4];
#pragma unroll
        for (int mt = 0; mt < 4; ++mt)
            a[mt] = *reinterpret_cast<const bf16x8*>(ab + abase + mt * 1024);
#pragma unroll
        for (int nt = 0; nt < 4; ++nt)
            b[nt] = *reinterpret_cast<const bf16x8*>(bb + bbase + nt * 1024);
        // 2) issue next-chunk stage into the other buffer (flies during MFMAs)
        if (c < 7) STAGE(c + 1, (c + 1) & 1);
        // 3) compute
#pragma unroll
        for (int mt = 0; mt < 4; ++mt)
#pragma unroll
            for (int nt = 0; nt < 4; ++nt)
                acc[mt][nt] = __builtin_amdgcn_mfma_f32_16x16x32_bf16(
                    a[mt], b[nt], acc[mt][nt], 0, 0, 0);
        // 4) one drain per phase (compiler: vmcnt(0)+lgkmcnt(0) before barrier)
        __syncthreads();
    }

    // ---- epilogue: L2, max, 5-kernel exp sum via squaring chain ----
    const float bw  = *bwp;
    const float ic4 = -1.44269504088896340736f / (bw * 16.0f + 1e-9f);

    float m = 0.0f;
    float ksum = 0.0f;
    const int rbase = i0 + wr * 64 + q * 4;
    const int cbase = j0 + wc * 64 + l15;
    float sb[4];
#pragma unroll
    for (int nt = 0; nt < 4; ++nt) sb[nt] = sq[cbase + nt * 16];
#pragma unroll
    for (int mt = 0; mt < 4; ++mt) {
        float sa[4];
#pragma unroll
        for (int r = 0; r < 4; ++r) sa[r] = sq[rbase + mt * 16 + r];
#pragma unroll
        for (int nt = 0; nt < 4; ++nt)
#pragma unroll
            for (int r = 0; r < 4; ++r) {
                float l2 = fmaxf(fmaf(-2.0f, acc[mt][nt][r], sa[r] + sb[nt]), 0.0f);
                m = fmaxf(m, l2);
                float e1  = exp2f(l2 * ic4);
                float e2  = e1 * e1;
                float e4  = e2 * e2;
                float e8  = e4 * e4;
                float e16 = e8 * e8;
                ksum += (e1 + e2) + (e4 + e8) + e16;
            }
    }

    double s = (double)ksum;
#pragma unroll
    for (int off = 32; off; off >>= 1) {
        s += __shfl_down(s, off);
        m  = fmaxf(m, __shfl_down(m, off));
    }
    if ((t & 63) == 0) { sred[w] = s; mred[w] = m; }
    __syncthreads();
    if (t == 0) {
        double st = sred[0] + sred[1] + sred[2] + sred[3];
        float  mt = fmaxf(fmaxf(mred[0], mred[1]), fmaxf(mred[2], mred[3]));
        atomicMax(maxBits, __float_as_int(mt));
        const int qq = (((i0 >= BHALF) ? 2 : 0) | ((j0 >= BHALF) ? 1 : 0));
        const int qT = (((j0 >= BHALF) ? 2 : 0) | ((i0 >= BHALF) ? 1 : 0));
        if (diag) {
            atomicAdd(&qsum[qq], st);
        } else if (qq == qT) {
            atomicAdd(&qsum[qq], 2.0 * st);      // mirror lower triangle
        } else {
            atomicAdd(&qsum[qq], st);
            atomicAdd(&qsum[qT], st);
        }
        __threadfence();
        lastFlag = (atomicAdd(gramCounter, 1) == 2079) ? 1u : 0u;
    }
    __syncthreads();
    if (lastFlag && t == 0) {
        __threadfence();
        double xx = atomicAdd(&qsum[0], 0.0);    // atomic-RMW: cross-XCD coherent
        double xy = atomicAdd(&qsum[1], 0.0);
        double yx = atomicAdd(&qsum[2], 0.0);
        double yy = atomicAdd(&qsum[3], 0.0);
        int    mb = atomicMax(maxBits, 0);
        const double denom = (double)BHALF * (double)BHALF;
        xx /= denom; xy /= denom; yx /= denom; yy /= denom;
        out[0] = (float)(xx + yy - xy - yx);
        out[1] = __int_as_float(mb);
        out[2] = (float)xx;
        out[3] = (float)yy;
        out[4] = (float)xy;
        out[5] = (float)yx;
    }
}

extern "C" void kernel_launch(void* const* d_in, const int* in_sizes, int n_in,
                              void* d_out, int out_size, void* d_ws, size_t ws_size,
                              hipStream_t stream) {
    const float* src = (const float*)d_in[0];
    const float* tgt = (const float*)d_in[1];
    float* out = (float*)d_out;

    double* qsum     = (double*)d_ws;
    int*    maxB     = (int*)   ((char*)d_ws + 32);
    float*  bwp      = (float*) ((char*)d_ws + 36);
    int*    gramCnt  = (int*)   ((char*)d_ws + 40);
    int*    prepCnt  = (int*)   ((char*)d_ws + 44);
    float*  sq       = (float*) ((char*)d_ws + 2112);
    unsigned short* hi = (unsigned short*)((char*)d_ws + 36864);
    float*  colpart  = (float*) ((char*)d_ws + 36864 + (size_t)NTOT * DIM * 2);
    float*  sqpart   = (float*) ((char*)d_ws + 36864 + (size_t)NTOT * DIM * 2 + 256 * 256 * 4);

    hipMemsetAsync(d_ws, 0, 64, stream);

    prep_kernel<<<NTOT / 32, 256, 0, stream>>>(src, tgt, sq, colpart, sqpart, hi,
                                               prepCnt, bwp);
    gram_kernel<<<2080, 256, 0, stream>>>(hi, sq, bwp, qsum, maxB, gramCnt, out);
}

// Round 10
// 199.771 us; speedup vs baseline: 1.0079x; 1.0004x over previous
//
#include <hip/hip_runtime.h>
#include <math.h>

// MMD loss, total = concat(source, target) [8192 x 256] f32.
// L2[i][j] = max(||ti||^2 + ||tj||^2 - 2 ti.tj, 0)
// bandwidth = sum(L2)/(n^2-n)/4, analytic: sum(L2) = 2n*S1 - 2*||sum_i ti||^2
// kernels = sum_{i=0..4} exp(-L2/(bw*2^i + 1e-9))
// outputs: [loss, max(L2), xx, yy, xy, yx]  (6 f32)
//
// Round 10 vs r9: depth-2 pipeline with counted vmcnt (T4). Fit of r6/r8 gives
// per-phase drain D~8us, W~46us -> drains are ~60% of gram. __syncthreads forces
// vmcnt(0) per phase; replace with triple-buffer + raw s_barrier + vmcnt(4):
//   prologue: STAGE(0), STAGE(1)
//   phase c:  vmcnt(4|2) [stage(c) done]; s_barrier; sched_barrier(0);
//             ds_read buf[c%3]; STAGE(c+2 -> buf[(c+2)%3]); setprio(1) MFMA x16.
// WAR safe with 3 buffers: stage(c+2) hits buf[(c-1)%3], whose reads finished
// before barrier c (lgkm-waited by phase c-1 MFMAs). Only c=7 drains vmcnt(0).

constexpr int NTOT  = 8192;
constexpr int BHALF = 4096;
constexpr int DIM   = 256;
constexpr int BM    = 128;
constexpr size_t CHUNK_BYTES = (size_t)(NTOT / 2) * 128;   // 524288 B per K-chunk

typedef __attribute__((ext_vector_type(8))) short bf16x8;
typedef __attribute__((ext_vector_type(4))) float f32x4;

#define GLOAD_LDS16(gp, lp)                                                      \
    __builtin_amdgcn_global_load_lds(                                            \
        (__attribute__((address_space(1))) const void*)(gp),                     \
        (__attribute__((address_space(3))) void*)(lp), 16, 0, 0)

// ws layout (bytes):
//   0       : double qsum[4]
//   32      : int    maxBits
//   36      : float  bandwidth
//   40      : int    gramCounter
//   44      : int    prepCounter
//   2112    : float  sq[8192]          (32 KB)
//   36864   : ushort hi[8192*256]      (4 MB, chunk-major swizzled)
//   4231168 : float  colpart[256][256] (256 KB per-block partial column sums)
//   4493312 : float  sqpart[256]       (1 KB per-block partial sums of sq)

__device__ __forceinline__ unsigned short rne_bf16(float f) {
    unsigned u = __float_as_uint(f);
    return (unsigned short)((u + 0x7fffu + ((u >> 16) & 1u)) >> 16);
}

// Fused: row norms (sq), column partial sums, f32 -> bf16 chunk-major swizzled,
// and (last block) the bandwidth reduction.
__global__ __launch_bounds__(256) void prep_kernel(
        const float* __restrict__ src, const float* __restrict__ tgt,
        float* __restrict__ sq, float* __restrict__ colpart,
        float* __restrict__ sqpart, unsigned short* __restrict__ hi,
        int* __restrict__ prepCounter, float* __restrict__ bwp) {
    __shared__ float  cs[4][256];
    __shared__ float  sblk[256];
    __shared__ double red[256];
    __shared__ unsigned lastFlag;
    const int t = threadIdx.x;
    const int w = t >> 6, l = t & 63;
    const int c   = l >> 3;            // K-chunk 0..7 (32 elems each)
    const int b16 = (l & 7) >> 1;      // granule index within chunk
    const int hs  = (l & 1) * 8;       // half of granule
    float c0 = 0.f, c1 = 0.f, c2 = 0.f, c3 = 0.f;
    float sqacc = 0.f;

#pragma unroll
    for (int it = 0; it < 8; ++it) {
        const int row = blockIdx.x * 32 + w * 8 + it;
        const float* p = (row < BHALF) ? src + (size_t)row * DIM
                                       : tgt + (size_t)(row - BHALF) * DIM;
        float4 v = reinterpret_cast<const float4*>(p)[l];
        float s = v.x * v.x + v.y * v.y + v.z * v.z + v.w * v.w;
        sqacc += s;
#pragma unroll
        for (int off = 32; off; off >>= 1) s += __shfl_down(s, off);
        if (l == 0) sq[row] = s;
        c0 += v.x; c1 += v.y; c2 += v.z; c3 += v.w;

        unsigned hp0 = (unsigned)rne_bf16(v.x) | ((unsigned)rne_bf16(v.y) << 16);
        unsigned hp1 = (unsigned)rne_bf16(v.z) | ((unsigned)rne_bf16(v.w) << 16);
        const int rp = row >> 1;
        const int g  = ((row & 1) << 2) | b16;
        const size_t byteoff = (size_t)c * CHUNK_BYTES + (size_t)rp * 128
                             + 16 * (g ^ (rp & 7)) + hs;
        *reinterpret_cast<uint2*>((char*)hi + byteoff) = make_uint2(hp0, hp1);
    }

    cs[w][l * 4 + 0] = c0; cs[w][l * 4 + 1] = c1;
    cs[w][l * 4 + 2] = c2; cs[w][l * 4 + 3] = c3;
    sblk[t] = sqacc;
    __syncthreads();
    colpart[blockIdx.x * 256 + t] = cs[0][t] + cs[1][t] + cs[2][t] + cs[3][t];
    for (int off = 128; off; off >>= 1) {
        if (t < off) sblk[t] += sblk[t + off];
        __syncthreads();
    }
    if (t == 0) sqpart[blockIdx.x] = sblk[0];

    // ---- last block reduces bandwidth ----
    __threadfence();
    if (t == 0) lastFlag = (atomicAdd(prepCounter, 1) == (NTOT / 32 - 1)) ? 1u : 0u;
    __syncthreads();
    if (lastFlag) {
        __threadfence();
        double v = 0.0;
        for (int b = 0; b < 256; ++b) v += (double)colpart[b * 256 + t];
        red[t] = v * v; __syncthreads();
        for (int off = 128; off; off >>= 1) {
            if (t < off) red[t] += red[t + off];
            __syncthreads();
        }
        double V2 = red[0]; __syncthreads();
        red[t] = (double)sqpart[t]; __syncthreads();
        for (int off = 128; off; off >>= 1) {
            if (t < off) red[t] += red[t + off];
            __syncthreads();
        }
        if (t == 0) {
            double S1 = red[0];
            const double n = (double)NTOT;
            double sumL2 = 2.0 * n * S1 - 2.0 * V2;
            *bwp = (float)(sumL2 / (n * n - n) / 4.0);
        }
    }
}

__global__ __launch_bounds__(256) void gram_kernel(
        const unsigned short* __restrict__ hi,
        const float* __restrict__ sq, const float* __restrict__ bwp,
        double* __restrict__ qsum, int* __restrict__ maxBits,
        int* __restrict__ gramCounter, float* __restrict__ out) {
    // XCD-aware swizzle over the 2080-block upper triangle (2080 = 8*260)
    const int tb = blockIdx.x;
    const int id = (tb & 7) * 260 + (tb >> 3);
    int k = 2079 - id;
    int u = (int)((sqrt((double)(8 * k + 1)) - 1.0) * 0.5);
    while ((u + 1) * (u + 2) / 2 <= k) ++u;
    while (u * (u + 1) / 2 > k) --u;
    const int by = 63 - u;
    const int bx = 63 - (k - u * (u + 1) / 2);
    const bool diag = (bx == by);

    __shared__ alignas(16) char ldsA[3][8192];   // 3 x 8 KB triple buffer
    __shared__ alignas(16) char ldsB[3][8192];
    __shared__ double sred[4];
    __shared__ float  mred[4];
    __shared__ unsigned lastFlag;

    const int i0 = by * BM;
    const int j0 = bx * BM;
    const char* Abase = (const char*)hi + (size_t)(i0 >> 1) * 128;
    const char* Bbase = (const char*)hi + (size_t)(j0 >> 1) * 128;

    const int t    = threadIdx.x;
    const int lane = t & 63;
    const int w    = t >> 6;       // 4 waves, 2x2 over the 128x128 tile
    const int wr   = w >> 1;
    const int wc   = w & 1;
    const int l15  = lane & 15;
    const int q    = lane >> 4;

    // per-thread fragment offset: row rL = half*64 + mt*16 + l15
    //   rp = rL>>1, pos = (((rL&1)<<2)|q) ^ (rp&7)  ->  folds to constant tail
    const int fragTail = (l15 >> 1) * 128
                       + 16 * (((((l15 & 1) << 2) | q)) ^ (l15 >> 1));
    const int abase = wr * 4096 + fragTail;
    const int bbase = wc * 4096 + fragTail;

    f32x4 acc[4][4] = {};

    auto STAGE = [&](int c, int buf) {
        const size_t cb = (size_t)c * CHUNK_BYTES + lane * 16;
#pragma unroll
        for (int it = 0; it < 2; ++it) {
            const int off = (it * 4 + w) * 1024;       // wave-uniform LDS dest
            GLOAD_LDS16(Abase + cb + off, &ldsA[buf][off]);
            if (!diag) GLOAD_LDS16(Bbase + cb + off, &ldsB[buf][off]);
        }
    };

    STAGE(0, 0);               // depth-2 prologue
    STAGE(1, 1);

#pragma unroll
    for (int c = 0; c < 8; ++c) {                  // 8 K-chunks of 32 bf16
        // counted wait: stage(c) retired, stage(c+1) may stay in flight
        if (c < 7) {
            if (diag) asm volatile("s_waitcnt vmcnt(2)" ::: "memory");
            else      asm volatile("s_waitcnt vmcnt(4)" ::: "memory");
        } else {
            asm volatile("s_waitcnt vmcnt(0)" ::: "memory");
        }
        __builtin_amdgcn_s_barrier();
        __builtin_amdgcn_sched_barrier(0);         // pin reads below barrier

        const char* ab = ldsA[c % 3];
        const char* bb = diag ? ldsA[c % 3] : ldsB[c % 3];
        bf16x8 a[4], b[4];
#pragma unroll
        for (int mt = 0; mt < 4; ++mt)
            a[mt] = *reinterpret_cast<const bf16x8*>(ab + abase + mt * 1024);
#pragma unroll
        for (int nt = 0; nt < 4; ++nt)
            b[nt] = *reinterpret_cast<const bf16x8*>(bb + bbase + nt * 1024);

        if (c < 6) STAGE(c + 2, (c + 2) % 3);      // keep 2 stages in flight

        __builtin_amdgcn_s_setprio(1);
#pragma unroll
        for (int mt = 0; mt < 4; ++mt)
#pragma unroll
            for (int nt = 0; nt < 4; ++nt)
                acc[mt][nt] = __builtin_amdgcn_mfma_f32_16x16x32_bf16(
                    a[mt], b[nt], acc[mt][nt], 0, 0, 0);
        __builtin_amdgcn_s_setprio(0);
    }

    // ---- epilogue: L2, max, 5-kernel exp sum via squaring chain ----
    const float bw  = *bwp;
    const float ic4 = -1.44269504088896340736f / (bw * 16.0f + 1e-9f);

    float m = 0.0f;
    float ksum = 0.0f;
    const int rbase = i0 + wr * 64 + q * 4;
    const int cbase = j0 + wc * 64 + l15;
    float sb[4];
#pragma unroll
    for (int nt = 0; nt < 4; ++nt) sb[nt] = sq[cbase + nt * 16];
#pragma unroll
    for (int mt = 0; mt < 4; ++mt) {
        float sa[4];
#pragma unroll
        for (int r = 0; r < 4; ++r) sa[r] = sq[rbase + mt * 16 + r];
#pragma unroll
        for (int nt = 0; nt < 4; ++nt)
#pragma unroll
            for (int r = 0; r < 4; ++r) {
                float l2 = fmaxf(fmaf(-2.0f, acc[mt][nt][r], sa[r] + sb[nt]), 0.0f);
                m = fmaxf(m, l2);
                float e1  = exp2f(l2 * ic4);
                float e2  = e1 * e1;
                float e4  = e2 * e2;
                float e8  = e4 * e4;
                float e16 = e8 * e8;
                ksum += (e1 + e2) + (e4 + e8) + e16;
            }
    }

    double s = (double)ksum;
#pragma unroll
    for (int off = 32; off; off >>= 1) {
        s += __shfl_down(s, off);
        m  = fmaxf(m, __shfl_down(m, off));
    }
    if ((t & 63) == 0) { sred[w] = s; mred[w] = m; }
    __syncthreads();
    if (t == 0) {
        double st = sred[0] + sred[1] + sred[2] + sred[3];
        float  mt = fmaxf(fmaxf(mred[0], mred[1]), fmaxf(mred[2], mred[3]));
        atomicMax(maxBits, __float_as_int(mt));
        const int qq = (((i0 >= BHALF) ? 2 : 0) | ((j0 >= BHALF) ? 1 : 0));
        const int qT = (((j0 >= BHALF) ? 2 : 0) | ((i0 >= BHALF) ? 1 : 0));
        if (diag) {
            atomicAdd(&qsum[qq], st);
        } else if (qq == qT) {
            atomicAdd(&qsum[qq], 2.0 * st);      // mirror lower triangle
        } else {
            atomicAdd(&qsum[qq], st);
            atomicAdd(&qsum[qT], st);
        }
        __threadfence();
        lastFlag = (atomicAdd(gramCounter, 1) == 2079) ? 1u : 0u;
    }
    __syncthreads();
    if (lastFlag && t == 0) {
        __threadfence();
        double xx = atomicAdd(&qsum[0], 0.0);    // atomic-RMW: cross-XCD coherent
        double xy = atomicAdd(&qsum[1], 0.0);
        double yx = atomicAdd(&qsum[2], 0.0);
        double yy = atomicAdd(&qsum[3], 0.0);
        int    mb = atomicMax(maxBits, 0);
        const double denom = (double)BHALF * (double)BHALF;
        xx /= denom; xy /= denom; yx /= denom; yy /= denom;
        out[0] = (float)(xx + yy - xy - yx);
        out[1] = __int_as_float(mb);
        out[2] = (float)xx;
        out[3] = (float)yy;
        out[4] = (float)xy;
        out[5] = (float)yx;
    }
}

extern "C" void kernel_launch(void* const* d_in, const int* in_sizes, int n_in,
                              void* d_out, int out_size, void* d_ws, size_t ws_size,
                              hipStream_t stream) {
    const float* src = (const float*)d_in[0];
    const float* tgt = (const float*)d_in[1];
    float* out = (float*)d_out;

    double* qsum     = (double*)d_ws;
    int*    maxB     = (int*)   ((char*)d_ws + 32);
    float*  bwp      = (float*) ((char*)d_ws + 36);
    int*    gramCnt  = (int*)   ((char*)d_ws + 40);
    int*    prepCnt  = (int*)   ((char*)d_ws + 44);
    float*  sq       = (float*) ((char*)d_ws + 2112);
    unsigned short* hi = (unsigned short*)((char*)d_ws + 36864);
    float*  colpart  = (float*) ((char*)d_ws + 36864 + (size_t)NTOT * DIM * 2);
    float*  sqpart   = (float*) ((char*)d_ws + 36864 + (size_t)NTOT * DIM * 2 + 256 * 256 * 4);

    hipMemsetAsync(d_ws, 0, 64, stream);

    prep_kernel<<<NTOT / 32, 256, 0, stream>>>(src, tgt, sq, colpart, sqpart, hi,
                                               prepCnt, bwp);
    gram_kernel<<<2080, 256, 0, stream>>>(hi, sq, bwp, qsum, maxB, gramCnt, out);
}

// Round 11
// 163.271 us; speedup vs baseline: 1.2332x; 1.2236x over previous
//
#include <hip/hip_runtime.h>
#include <math.h>

// MMD loss, total = concat(source, target) [8192 x 256] f32.
// outputs: [loss, max(L2), xx, yy, xy, yx]  (6 f32)
//
// Round 11, three fixes from r10 post-mortem:
//  1. The ~50us hidden tax: bandwidth reduction ran 256 serial strided L2 reads
//     on ONE CU (since r2!). Now: u64 fixed-point HW atomics from all prep
//     blocks; last prep block reads 257 u64 (~2us).
//  2. qsum f64 atomicAdd = CAS loop on AMD by default, ~3000 contended ops on
//     one line. Now: u64 fixed-point (scale 2^20), one 64B line per quadrant.
//  3. Phase-overhead fit (r6 4ph=78, r8/9/10 8ph=108 -> 7.5us/phase + 48):
//     BK=128 -> 2 phases, single-buffer 64KB LDS.

constexpr int NTOT  = 8192;
constexpr int BHALF = 4096;
constexpr int DIM   = 256;
constexpr int BM    = 128;
constexpr size_t CHUNK_BYTES = (size_t)(NTOT / 2) * 128;   // 512 KB per K-chunk of 32

constexpr double QSC   = 1048576.0;     // 2^20 qsum fixed-point scale
constexpr double CSC   = 16777216.0;    // 2^24 colsum scale
constexpr double SSC   = 1048576.0;     // 2^20 sum-of-squares scale

typedef __attribute__((ext_vector_type(8))) short bf16x8;
typedef __attribute__((ext_vector_type(4))) float f32x4;

#define GLOAD_LDS16(gp, lp)                                                      \
    __builtin_amdgcn_global_load_lds(                                            \
        (__attribute__((address_space(1))) const void*)(gp),                     \
        (__attribute__((address_space(3))) void*)(lp), 16, 0, 0)

// ws layout (bytes):
//   0,64,128,192 : u64 qsumFx[4]      (one cache line each)
//   256   : int  maxBits
//   260   : float bandwidth
//   264   : int  gramCounter
//   268   : int  prepCounter
//   272   : u64  sqFx
//   320   : u64  vcolFx[256]          (2 KB)      -- memset covers 0..2368
//   2432  : float sq[8192]            (32 KB)
//   36864 : ushort hi[8192*256]       (4 MB, chunk-major swizzled)

__device__ __forceinline__ unsigned short rne_bf16(float f) {
    unsigned u = __float_as_uint(f);
    return (unsigned short)((u + 0x7fffu + ((u >> 16) & 1u)) >> 16);
}

__device__ __forceinline__ void atomicAddFx(unsigned long long* p, double v, double sc) {
    long long q = __double2ll_rn(v * sc);
    atomicAdd(p, (unsigned long long)q);   // two's complement: signed-safe
}

// Fused: row norms (sq), col sums + sum(sq) via u64 fixed-point HW atomics,
// f32 -> bf16 chunk-major swizzled, last block computes bandwidth.
__global__ __launch_bounds__(256) void prep_kernel(
        const float* __restrict__ src, const float* __restrict__ tgt,
        float* __restrict__ sq, unsigned long long* __restrict__ vcolFx,
        unsigned long long* __restrict__ sqFx, unsigned short* __restrict__ hi,
        int* __restrict__ prepCounter, float* __restrict__ bwp) {
    __shared__ float  cs[4][256];
    __shared__ float  sblk[256];
    __shared__ double red[256];
    __shared__ unsigned lastFlag;
    const int t = threadIdx.x;
    const int w = t >> 6, l = t & 63;
    const int c   = l >> 3;            // K-chunk 0..7 (32 elems each)
    const int b16 = (l & 7) >> 1;      // granule index within chunk
    const int hs  = (l & 1) * 8;       // half of granule
    float c0 = 0.f, c1 = 0.f, c2 = 0.f, c3 = 0.f;
    float sqacc = 0.f;

#pragma unroll
    for (int it = 0; it < 8; ++it) {
        const int row = blockIdx.x * 32 + w * 8 + it;
        const float* p = (row < BHALF) ? src + (size_t)row * DIM
                                       : tgt + (size_t)(row - BHALF) * DIM;
        float4 v = reinterpret_cast<const float4*>(p)[l];
        float s = v.x * v.x + v.y * v.y + v.z * v.z + v.w * v.w;
        sqacc += s;
#pragma unroll
        for (int off = 32; off; off >>= 1) s += __shfl_down(s, off);
        if (l == 0) sq[row] = s;
        c0 += v.x; c1 += v.y; c2 += v.z; c3 += v.w;

        unsigned hp0 = (unsigned)rne_bf16(v.x) | ((unsigned)rne_bf16(v.y) << 16);
        unsigned hp1 = (unsigned)rne_bf16(v.z) | ((unsigned)rne_bf16(v.w) << 16);
        const int rp = row >> 1;
        const int g  = ((row & 1) << 2) | b16;
        const size_t byteoff = (size_t)c * CHUNK_BYTES + (size_t)rp * 128
                             + 16 * (g ^ (rp & 7)) + hs;
        *reinterpret_cast<uint2*>((char*)hi + byteoff) = make_uint2(hp0, hp1);
    }

    cs[w][l * 4 + 0] = c0; cs[w][l * 4 + 1] = c1;
    cs[w][l * 4 + 2] = c2; cs[w][l * 4 + 3] = c3;
    sblk[t] = sqacc;
    __syncthreads();
    // column-t partial for this block -> one HW u64 atomic per thread
    atomicAddFx(&vcolFx[t], (double)(cs[0][t] + cs[1][t] + cs[2][t] + cs[3][t]), CSC);
    for (int off = 128; off; off >>= 1) {
        if (t < off) sblk[t] += sblk[t + off];
        __syncthreads();
    }
    if (t == 0) atomicAddFx(sqFx, (double)sblk[0], SSC);

    // ---- last block computes bandwidth (parallel, ~2us) ----
    __threadfence();
    if (t == 0) lastFlag = (atomicAdd(prepCounter, 1) == (NTOT / 32 - 1)) ? 1u : 0u;
    __syncthreads();
    if (lastFlag) {
        __threadfence();
        double v = (double)(long long)atomicAdd(&vcolFx[t], 0ULL) / CSC;
        red[t] = v * v; __syncthreads();
        for (int off = 128; off; off >>= 1) {
            if (t < off) red[t] += red[t + off];
            __syncthreads();
        }
        if (t == 0) {
            double V2 = red[0];
            double S1 = (double)(long long)atomicAdd(sqFx, 0ULL) / SSC;
            const double n = (double)NTOT;
            double sumL2 = 2.0 * n * S1 - 2.0 * V2;
            *bwp = (float)(sumL2 / (n * n - n) / 4.0);
        }
    }
}

__global__ __launch_bounds__(256) void gram_kernel(
        const unsigned short* __restrict__ hi,
        const float* __restrict__ sq, const float* __restrict__ bwp,
        unsigned long long* __restrict__ qsumFx, int* __restrict__ maxBits,
        int* __restrict__ gramCounter, float* __restrict__ out) {
    // XCD-aware swizzle over the 2080-block upper triangle (2080 = 8*260)
    const int tb = blockIdx.x;
    const int id = (tb & 7) * 260 + (tb >> 3);
    int k = 2079 - id;
    int u = (int)((sqrt((double)(8 * k + 1)) - 1.0) * 0.5);
    while ((u + 1) * (u + 2) / 2 <= k) ++u;
    while (u * (u + 1) / 2 > k) --u;
    const int by = 63 - u;
    const int bx = 63 - (k - u * (u + 1) / 2);
    const bool diag = (bx == by);

    __shared__ alignas(16) char ldsA[4][8192];   // 32 KB: 4 chunk sub-buffers
    __shared__ alignas(16) char ldsB[4][8192];   // 32 KB
    __shared__ double sred[4];
    __shared__ float  mred[4];
    __shared__ unsigned lastFlag;

    const int i0 = by * BM;
    const int j0 = bx * BM;
    const char* Abase = (const char*)hi + (size_t)(i0 >> 1) * 128;
    const char* Bbase = (const char*)hi + (size_t)(j0 >> 1) * 128;

    const int t    = threadIdx.x;
    const int lane = t & 63;
    const int w    = t >> 6;       // 4 waves, 2x2 over the 128x128 tile
    const int wr   = w >> 1;
    const int wc   = w & 1;
    const int l15  = lane & 15;
    const int q    = lane >> 4;

    // per-thread fragment offset within an 8KB chunk buffer
    const int fragTail = (l15 >> 1) * 128
                       + 16 * (((((l15 & 1) << 2) | q)) ^ (l15 >> 1));
    const int abase = wr * 4096 + fragTail;
    const int bbase = wc * 4096 + fragTail;

    f32x4 acc[4][4] = {};

    auto STAGE = [&](int p) {                      // stage 4 chunks (K=128)
#pragma unroll
        for (int i = 0; i < 4; ++i) {
            const size_t cb = (size_t)(p * 4 + i) * CHUNK_BYTES + lane * 16;
#pragma unroll
            for (int it = 0; it < 2; ++it) {
                const int off = (it * 4 + w) * 1024;   // wave-uniform LDS dest
                GLOAD_LDS16(Abase + cb + off, &ldsA[i][off]);
                if (!diag) GLOAD_LDS16(Bbase + cb + off, &ldsB[i][off]);
            }
        }
    };

#pragma unroll
    for (int p = 0; p < 2; ++p) {                  // 2 phases of K=128
        if (p) __syncthreads();                    // WAR: computes done
        STAGE(p);
        __syncthreads();                           // stage drained
        __builtin_amdgcn_s_setprio(1);
#pragma unroll
        for (int i = 0; i < 4; ++i) {              // 4 k-steps of 32
            const char* ab = ldsA[i];
            const char* bb = diag ? ldsA[i] : ldsB[i];
            bf16x8 a[4], b[4];
#pragma unroll
            for (int mt = 0; mt < 4; ++mt)
                a[mt] = *reinterpret_cast<const bf16x8*>(ab + abase + mt * 1024);
#pragma unroll
            for (int nt = 0; nt < 4; ++nt)
                b[nt] = *reinterpret_cast<const bf16x8*>(bb + bbase + nt * 1024);
#pragma unroll
            for (int mt = 0; mt < 4; ++mt)
#pragma unroll
                for (int nt = 0; nt < 4; ++nt)
                    acc[mt][nt] = __builtin_amdgcn_mfma_f32_16x16x32_bf16(
                        a[mt], b[nt], acc[mt][nt], 0, 0, 0);
        }
        __builtin_amdgcn_s_setprio(0);
    }

    // ---- epilogue: L2, max, 5-kernel exp sum via squaring chain ----
    const float bw  = *bwp;
    const float ic4 = -1.44269504088896340736f / (bw * 16.0f + 1e-9f);

    float m = 0.0f;
    float ksum = 0.0f;
    const int rbase = i0 + wr * 64 + q * 4;
    const int cbase = j0 + wc * 64 + l15;
    float sb[4];
#pragma unroll
    for (int nt = 0; nt < 4; ++nt) sb[nt] = sq[cbase + nt * 16];
#pragma unroll
    for (int mt = 0; mt < 4; ++mt) {
        float sa[4];
#pragma unroll
        for (int r = 0; r < 4; ++r) sa[r] = sq[rbase + mt * 16 + r];
#pragma unroll
        for (int nt = 0; nt < 4; ++nt)
#pragma unroll
            for (int r = 0; r < 4; ++r) {
                float l2 = fmaxf(fmaf(-2.0f, acc[mt][nt][r], sa[r] + sb[nt]), 0.0f);
                m = fmaxf(m, l2);
                float e1  = exp2f(l2 * ic4);
                float e2  = e1 * e1;
                float e4  = e2 * e2;
                float e8  = e4 * e4;
                float e16 = e8 * e8;
                ksum += (e1 + e2) + (e4 + e8) + e16;
            }
    }

    double s = (double)ksum;
#pragma unroll
    for (int off = 32; off; off >>= 1) {
        s += __shfl_down(s, off);
        m  = fmaxf(m, __shfl_down(m, off));
    }
    if ((t & 63) == 0) { sred[w] = s; mred[w] = m; }
    __syncthreads();
    if (t == 0) {
        double st = sred[0] + sred[1] + sred[2] + sred[3];
        float  mt = fmaxf(fmaxf(mred[0], mred[1]), fmaxf(mred[2], mred[3]));
        atomicMax(maxBits, __float_as_int(mt));
        const int qq = (((i0 >= BHALF) ? 2 : 0) | ((j0 >= BHALF) ? 1 : 0));
        const int qT = (((j0 >= BHALF) ? 2 : 0) | ((i0 >= BHALF) ? 1 : 0));
        // u64 fixed-point HW atomics, one 64B line per quadrant (stride 8 u64)
        if (diag) {
            atomicAddFx(&qsumFx[qq * 8], st, QSC);
        } else if (qq == qT) {
            atomicAddFx(&qsumFx[qq * 8], 2.0 * st, QSC);
        } else {
            atomicAddFx(&qsumFx[qq * 8], st, QSC);
            atomicAddFx(&qsumFx[qT * 8], st, QSC);
        }
        __threadfence();
        lastFlag = (atomicAdd(gramCounter, 1) == 2079) ? 1u : 0u;
    }
    __syncthreads();
    if (lastFlag && t == 0) {
        __threadfence();
        double xx = (double)(long long)atomicAdd(&qsumFx[0],  0ULL) / QSC;
        double xy = (double)(long long)atomicAdd(&qsumFx[8],  0ULL) / QSC;
        double yx = (double)(long long)atomicAdd(&qsumFx[16], 0ULL) / QSC;
        double yy = (double)(long long)atomicAdd(&qsumFx[24], 0ULL) / QSC;
        int    mb = atomicMax(maxBits, 0);
        const double denom = (double)BHALF * (double)BHALF;
        xx /= denom; xy /= denom; yx /= denom; yy /= denom;
        out[0] = (float)(xx + yy - xy - yx);
        out[1] = __int_as_float(mb);
        out[2] = (float)xx;
        out[3] = (float)yy;
        out[4] = (float)xy;
        out[5] = (float)yx;
    }
}

extern "C" void kernel_launch(void* const* d_in, const int* in_sizes, int n_in,
                              void* d_out, int out_size, void* d_ws, size_t ws_size,
                              hipStream_t stream) {
    const float* src = (const float*)d_in[0];
    const float* tgt = (const float*)d_in[1];
    float* out = (float*)d_out;

    unsigned long long* qsumFx = (unsigned long long*)d_ws;          // stride-8 u64
    int*    maxB    = (int*)   ((char*)d_ws + 256);
    float*  bwp     = (float*) ((char*)d_ws + 260);
    int*    gramCnt = (int*)   ((char*)d_ws + 264);
    int*    prepCnt = (int*)   ((char*)d_ws + 268);
    unsigned long long* sqFx   = (unsigned long long*)((char*)d_ws + 272);
    unsigned long long* vcolFx = (unsigned long long*)((char*)d_ws + 320);
    float*  sq      = (float*) ((char*)d_ws + 2432);
    unsigned short* hi = (unsigned short*)((char*)d_ws + 36864);

    hipMemsetAsync(d_ws, 0, 2368, stream);

    prep_kernel<<<NTOT / 32, 256, 0, stream>>>(src, tgt, sq, vcolFx, sqFx, hi,
                                               prepCnt, bwp);
    gram_kernel<<<2080, 256, 0, stream>>>(hi, sq, bwp, qsumFx, maxB, gramCnt, out);
}